// Round 7
// baseline (450.842 us; speedup 1.0000x reference)
//
#include <hip/hip_runtime.h>
#include <hip/hip_bf16.h>

// ---------------- problem constants ----------------
constexpr int N_NODES = 50000;
constexpr int E_TOTAL = 800000;
constexpr int EB   = 64;              // edges per tile
constexpr int NT   = E_TOTAL / EB;    // 12500 tiles
constexpr int GRID = 512;             // persistent blocks, 2 per CU
constexpr int TPB  = 512;             // 8 waves: 4 n-groups x 2 e-groups

typedef __attribute__((ext_vector_type(8)))  short bf16x8;
typedef __attribute__((ext_vector_type(16))) float f32x16;

// ---------------- workspace byte offsets ----------------
// bf16 images, n-major rows, bias folded at k=100 (k=8 for W1); act pads carry 1.0.
constexpr size_t WS_CNT = 0;                   // N_NODES f32
constexpr size_t WS_W1  = 200704;              // [128 n][32 B]   (K=16)
constexpr size_t WS_W2  = WS_W1 + 4096;        // [128 n][256 B]  (K=128)
constexpr size_t WS_W3  = WS_W2 + 32768;       // [128 n][256 B]
constexpr size_t WS_W4  = WS_W3 + 32768;       // [256 n][256 B]

// ---------------- LDS byte offsets (64000 B -> 2 blocks/CU) ----------------
constexpr int L_HA  = 0;                 // [64 e][272 B] bf16 (stride 17x16B)
constexpr int L_HB  = 17408;             // [64 e][272 B]
constexpr int L_EA  = 34816;             // [64 e][48 B] bf16 (16 k; 1.0 at k=8)
constexpr int L_XS  = 37888;             // [64 e][80 B] f32 (16 used)
constexpr int L_MSG = 43008;             // 4 slabs x [64 e][80 B] f32 (16 used)
constexpr int L_DST = 63488;             // 2 x 64 i32
constexpr int L_TOT = 64000;

__device__ inline unsigned short bfb(float f) {
    __hip_bfloat16 h = __float2bfloat16(f);
    return __builtin_bit_cast(unsigned short, h);
}
__device__ inline unsigned pk2(float a, float b) {
    return (unsigned)bfb(a) | ((unsigned)bfb(b) << 16);
}
__device__ inline unsigned pk2r(float a, float b) {   // relu + pack
    return pk2(fmaxf(a, 0.f), fmaxf(b, 0.f));
}

// K=128 layer, 32x32x16 MFMA, swapped operands: D[n][e] = sum_k W[n][k] h[e][k].
// A (weights) from registers; B (activations) rows [e][272B].
template<int IN_OFF, int OUT_OFF>
__device__ inline void layer32(char* sm, const bf16x8 (&wf)[8],
                               int wn, int we, int l31, int g)
{
    const int e = 32 * we + l31;
    f32x16 acc = {};
#pragma unroll
    for (int ks = 0; ks < 8; ++ks) {
        const bf16x8 b = *reinterpret_cast<const bf16x8*>(sm + IN_OFF + e * 272 + ks * 32 + g * 16);
        acc = __builtin_amdgcn_mfma_f32_32x32x16_bf16(wf[ks], b, acc, 0, 0, 0);
    }
#pragma unroll
    for (int q = 0; q < 4; ++q) {
        uint2 pk;
        pk.x = pk2r(acc[4 * q + 0], acc[4 * q + 1]);
        pk.y = pk2r(acc[4 * q + 2], acc[4 * q + 3]);
        *reinterpret_cast<uint2*>(sm + OUT_OFF + e * 272 + 64 * wn + 16 * q + 8 * g) = pk;
    }
}

__global__ __launch_bounds__(TPB, 4)
void edge_kernel(const float* __restrict__ x, const int* __restrict__ eidx,
                 const float* __restrict__ ea, const char* __restrict__ ws,
                 float* __restrict__ out, float* __restrict__ cnt)
{
    extern __shared__ char sm[];
    const int t    = threadIdx.x;
    const int lane = t & 63;
    const int wave = t >> 6;
    const int wn   = wave & 3, we = wave >> 2;   // 4 n-groups x 2 e-groups
    const int l31  = lane & 31, g = lane >> 5;
    int* dsti = reinterpret_cast<int*>(sm + L_DST);

    // ---- weight fragments (A-operands); compiler keeps/remats under 128 VGPR ----
    bf16x8 wf1, wf2[8], wf3[8], wf4[2][8];
    {
        const int n = 32 * wn + l31;
        wf1 = *reinterpret_cast<const bf16x8*>(ws + WS_W1 + n * 32 + g * 16);
#pragma unroll
        for (int ks = 0; ks < 8; ++ks) {
            wf2[ks] = *reinterpret_cast<const bf16x8*>(ws + WS_W2 + n * 256 + ks * 32 + g * 16);
            wf3[ks] = *reinterpret_cast<const bf16x8*>(ws + WS_W3 + n * 256 + ks * 32 + g * 16);
        }
#pragma unroll
        for (int mf = 0; mf < 2; ++mf) {
            const int n4 = 64 * wn + 32 * mf + l31;
#pragma unroll
            for (int ks = 0; ks < 8; ++ks)
                wf4[mf][ks] = *reinterpret_cast<const bf16x8*>(ws + WS_W4 + n4 * 256 + ks * 32 + g * 16);
        }
    }

    // ---- constant upper half of EA rows: k=8 -> 1.0, k=9..15 -> 0 ----
    if (t < 64)
        *reinterpret_cast<uint4*>(sm + L_EA + t * 48 + 16) = make_uint4(0x3F80u, 0u, 0u, 0u);

    // ---- stage first tile into registers ----
    float4 eaR, xvR; int dstR = 0;
    {
        const int e0 = blockIdx.x * EB;
        if (t < 128) eaR = *reinterpret_cast<const float4*>(&ea[(size_t)(e0 + (t >> 1)) * 8 + (t & 1) * 4]);
        if (t < 256) {
            const int s = eidx[e0 + (t >> 2)];
            xvR = *reinterpret_cast<const float4*>(&x[(size_t)s * 16 + (t & 3) * 4]);
        }
        if (t < 64) dstR = eidx[E_TOTAL + e0 + t];
    }

    int p = 0;
    bool has_prev = false;
    for (int tile = blockIdx.x; tile < NT; tile += GRID) {
        // ---- S: scatter prev tile's messages; stage this tile; prefetch next ----
        if (has_prev && t < 256) {
            const int e = t >> 2, o0 = (t & 3) * 4;
            const float4 s0 = *reinterpret_cast<const float4*>(sm + L_MSG + 0 * 5120 + e * 80 + o0 * 4);
            const float4 s1 = *reinterpret_cast<const float4*>(sm + L_MSG + 1 * 5120 + e * 80 + o0 * 4);
            const float4 s2 = *reinterpret_cast<const float4*>(sm + L_MSG + 2 * 5120 + e * 80 + o0 * 4);
            const float4 s3 = *reinterpret_cast<const float4*>(sm + L_MSG + 3 * 5120 + e * 80 + o0 * 4);
            const int d = dsti[(p ^ 1) * 64 + e];
            unsafeAtomicAdd(&out[(size_t)d * 16 + o0 + 0], s0.x + s1.x + s2.x + s3.x);
            unsafeAtomicAdd(&out[(size_t)d * 16 + o0 + 1], s0.y + s1.y + s2.y + s3.y);
            unsafeAtomicAdd(&out[(size_t)d * 16 + o0 + 2], s0.z + s1.z + s2.z + s3.z);
            unsafeAtomicAdd(&out[(size_t)d * 16 + o0 + 3], s0.w + s1.w + s2.w + s3.w);
            if ((t & 3) == 0) unsafeAtomicAdd(&cnt[d], 1.0f);
        }
        if (t < 128) {   // ea -> bf16, lower 16B of EA row
            uint2 pk; pk.x = pk2(eaR.x, eaR.y); pk.y = pk2(eaR.z, eaR.w);
            *reinterpret_cast<uint2*>(sm + L_EA + (t >> 1) * 48 + 8 * (t & 1)) = pk;
        }
        if (t < 256)
            *reinterpret_cast<float4*>(sm + L_XS + (t >> 2) * 80 + (t & 3) * 16) = xvR;
        if (t < 64) dsti[p * 64 + t] = dstR;

        const int nxt = tile + GRID;
        if (nxt < NT) {
            const int e0 = nxt * EB;
            if (t < 128) eaR = *reinterpret_cast<const float4*>(&ea[(size_t)(e0 + (t >> 1)) * 8 + (t & 1) * 4]);
            if (t < 256) {
                const int s = eidx[e0 + (t >> 2)];
                xvR = *reinterpret_cast<const float4*>(&x[(size_t)s * 16 + (t & 3) * 4]);
            }
            if (t < 64) dstR = eidx[E_TOTAL + e0 + t];
        }
        __syncthreads();                                            // A

        // ---- L1: K=16 (8 attrs + bias col), EA -> HA ----
        {
            const int e = 32 * we + l31;
            const bf16x8 b = *reinterpret_cast<const bf16x8*>(sm + L_EA + e * 48 + g * 16);
            f32x16 acc = {};
            acc = __builtin_amdgcn_mfma_f32_32x32x16_bf16(wf1, b, acc, 0, 0, 0);
#pragma unroll
            for (int q = 0; q < 4; ++q) {
                uint2 pk;
                pk.x = pk2r(acc[4 * q + 0], acc[4 * q + 1]);
                pk.y = pk2r(acc[4 * q + 2], acc[4 * q + 3]);
                *reinterpret_cast<uint2*>(sm + L_HA + e * 272 + 64 * wn + 16 * q + 8 * g) = pk;
            }
        }
        __syncthreads();                                            // B
        layer32<L_HA, L_HB>(sm, wf2, wn, we, l31, g);               // L2
        __syncthreads();                                            // C
        layer32<L_HB, L_HA>(sm, wf3, wn, we, l31, g);               // L3
        __syncthreads();                                            // D

        // ---- L4: w[e][n] for this wave's 64 n (W4 from regs) + fold x ----
        {
            const int e = 32 * we + l31;
            f32x16 acc4[2] = {};
#pragma unroll
            for (int ks = 0; ks < 8; ++ks) {
                const bf16x8 b = *reinterpret_cast<const bf16x8*>(sm + L_HA + e * 272 + ks * 32 + g * 16);
#pragma unroll
                for (int mf = 0; mf < 2; ++mf)
                    acc4[mf] = __builtin_amdgcn_mfma_f32_32x32x16_bf16(wf4[mf][ks], b, acc4[mf], 0, 0, 0);
            }
            // fold: n = 64wn + 32mf + nloc; i = n>>4 = 4wn + 2mf + (reg>>3); o = n&15
            const float4 xv = *reinterpret_cast<const float4*>(sm + L_XS + e * 80 + wn * 16);
            float pr[8] = {0.f, 0.f, 0.f, 0.f, 0.f, 0.f, 0.f, 0.f};
#pragma unroll
            for (int mf = 0; mf < 2; ++mf)
#pragma unroll
                for (int reg = 0; reg < 16; ++reg) {
                    const float xi = (&xv.x)[2 * mf + (reg >> 3)];
                    const int s = (reg & 3) + 4 * ((reg >> 2) & 1);
                    pr[s] = fmaf(xi, acc4[mf][reg], pr[s]);
                }
            // o = {0..3}+4g at byte 16g ; o = {8..11}+4g at byte 32+16g
            *reinterpret_cast<float4*>(sm + L_MSG + wn * 5120 + e * 80 + 16 * g) =
                make_float4(pr[0], pr[1], pr[2], pr[3]);
            *reinterpret_cast<float4*>(sm + L_MSG + wn * 5120 + e * 80 + 32 + 16 * g) =
                make_float4(pr[4], pr[5], pr[6], pr[7]);
        }
        __syncthreads();                                            // E
        p ^= 1;
        has_prev = true;
    }

    // ---- trailing scatter ----
    if (has_prev && t < 256) {
        const int e = t >> 2, o0 = (t & 3) * 4;
        const float4 s0 = *reinterpret_cast<const float4*>(sm + L_MSG + 0 * 5120 + e * 80 + o0 * 4);
        const float4 s1 = *reinterpret_cast<const float4*>(sm + L_MSG + 1 * 5120 + e * 80 + o0 * 4);
        const float4 s2 = *reinterpret_cast<const float4*>(sm + L_MSG + 2 * 5120 + e * 80 + o0 * 4);
        const float4 s3 = *reinterpret_cast<const float4*>(sm + L_MSG + 3 * 5120 + e * 80 + o0 * 4);
        const int d = dsti[(p ^ 1) * 64 + e];
        unsafeAtomicAdd(&out[(size_t)d * 16 + o0 + 0], s0.x + s1.x + s2.x + s3.x);
        unsafeAtomicAdd(&out[(size_t)d * 16 + o0 + 1], s0.y + s1.y + s2.y + s3.y);
        unsafeAtomicAdd(&out[(size_t)d * 16 + o0 + 2], s0.z + s1.z + s2.z + s3.z);
        unsafeAtomicAdd(&out[(size_t)d * 16 + o0 + 3], s0.w + s1.w + s2.w + s3.w);
        if ((t & 3) == 0) unsafeAtomicAdd(&cnt[d], 1.0f);
    }
}

// bf16 weight images with bias folded (k=100 col; k=8 for W1) + zero cnt
__global__ __launch_bounds__(256)
void prep_kernel(const float* __restrict__ W1, const float* __restrict__ b1,
                 const float* __restrict__ W2, const float* __restrict__ b2,
                 const float* __restrict__ W3, const float* __restrict__ b3,
                 const float* __restrict__ W4, const float* __restrict__ b4,
                 char* __restrict__ ws)
{
    const int id = blockIdx.x * 256 + threadIdx.x;
    if (id < N_NODES) reinterpret_cast<float*>(ws + WS_CNT)[id] = 0.f;
    if (id >= 67584) return;
    if (id < 2048) {                       // W1 img [128 n][16 k]
        const int n = id >> 4, k = id & 15;
        float v = 0.f;
        if (k < 8)        { if (n < 100) v = W1[k * 100 + n]; }
        else if (k == 8)  { v = (n < 100) ? b1[n] : (n == 100 ? 1.f : 0.f); }
        reinterpret_cast<unsigned short*>(ws + WS_W1)[id] = bfb(v);
    } else if (id < 18432) {               // W2 img [128][128]
        const int j = id - 2048, n = j >> 7, k = j & 127;
        float v = 0.f;
        if (k < 100)       { if (n < 100) v = W2[k * 100 + n]; }
        else if (k == 100) { v = (n < 100) ? b2[n] : (n == 100 ? 1.f : 0.f); }
        reinterpret_cast<unsigned short*>(ws + WS_W2)[j] = bfb(v);
    } else if (id < 34816) {               // W3 img [128][128]
        const int j = id - 18432, n = j >> 7, k = j & 127;
        float v = 0.f;
        if (k < 100)       { if (n < 100) v = W3[k * 100 + n]; }
        else if (k == 100) { v = (n < 100) ? b3[n] : (n == 100 ? 1.f : 0.f); }
        reinterpret_cast<unsigned short*>(ws + WS_W3)[j] = bfb(v);
    } else {                               // W4 img [256][128]
        const int j = id - 34816, n = j >> 7, k = j & 127;
        float v = 0.f;
        if (k < 100)       v = W4[k * 256 + n];
        else if (k == 100) v = b4[n];
        reinterpret_cast<unsigned short*>(ws + WS_W4)[j] = bfb(v);
    }
}

// out[n][o] = x[n]@root[:,o] + out[n][o]/max(cnt[n],1) + bias[o]   (in place)
__global__ __launch_bounds__(256)
void node_kernel(const float* __restrict__ x, const float* __restrict__ root,
                 const float* __restrict__ bias, const float* __restrict__ cnt,
                 float* __restrict__ out)
{
    const int n = blockIdx.x * blockDim.x + threadIdx.x;
    if (n >= N_NODES) return;
    float xr[16];
#pragma unroll
    for (int q = 0; q < 4; ++q) {
        const float4 v = *reinterpret_cast<const float4*>(&x[(size_t)n * 16 + 4 * q]);
        xr[4 * q] = v.x; xr[4 * q + 1] = v.y; xr[4 * q + 2] = v.z; xr[4 * q + 3] = v.w;
    }
    const float inv = 1.f / fmaxf(cnt[n], 1.f);
#pragma unroll
    for (int q = 0; q < 4; ++q) {
        float4 o4 = *reinterpret_cast<float4*>(&out[(size_t)n * 16 + 4 * q]);
        float res[4];
#pragma unroll
        for (int j = 0; j < 4; ++j) {
            const int o = 4 * q + j;
            float dot = 0.f;
#pragma unroll
            for (int i = 0; i < 16; ++i)
                dot = fmaf(xr[i], root[i * 16 + o], dot);
            res[j] = dot + (&o4.x)[j] * inv + bias[o];
        }
        *reinterpret_cast<float4*>(&out[(size_t)n * 16 + 4 * q]) = make_float4(res[0], res[1], res[2], res[3]);
    }
}

extern "C" void kernel_launch(void* const* d_in, const int* in_sizes, int n_in,
                              void* d_out, int out_size, void* d_ws, size_t ws_size,
                              hipStream_t stream)
{
    const float* x    = (const float*)d_in[0];
    const int*   eidx = (const int*)  d_in[1];
    const float* ea   = (const float*)d_in[2];
    const float* W1   = (const float*)d_in[3];
    const float* b1   = (const float*)d_in[4];
    const float* W2   = (const float*)d_in[5];
    const float* b2   = (const float*)d_in[6];
    const float* W3   = (const float*)d_in[7];
    const float* b3   = (const float*)d_in[8];
    const float* W4   = (const float*)d_in[9];
    const float* b4   = (const float*)d_in[10];
    const float* root = (const float*)d_in[11];
    const float* bias = (const float*)d_in[12];
    float* out = (float*)d_out;
    char*  ws  = (char*)d_ws;
    float* cnt = (float*)d_ws;

    (void)in_sizes; (void)n_in; (void)ws_size;

    hipFuncSetAttribute((const void*)edge_kernel,
                        hipFuncAttributeMaxDynamicSharedMemorySize, L_TOT);

    hipMemsetAsync(d_out, 0, (size_t)out_size * sizeof(float), stream);

    hipLaunchKernelGGL(prep_kernel, dim3(264), dim3(256), 0, stream,
                       W1, b1, W2, b2, W3, b3, W4, b4, ws);
    hipLaunchKernelGGL(edge_kernel, dim3(GRID), dim3(TPB), L_TOT, stream,
                       x, eidx, ea, ws, out, cnt);
    hipLaunchKernelGGL(node_kernel, dim3((N_NODES + 255) / 256), dim3(256), 0, stream,
                       x, root, bias, cnt, out);
}

// Round 8
// 327.351 us; speedup vs baseline: 1.3772x; 1.3772x over previous
//
#include <hip/hip_runtime.h>
#include <hip/hip_bf16.h>

// ---------------- problem constants ----------------
constexpr int N_NODES = 50000;
constexpr int E_TOTAL = 800000;
constexpr int EB   = 64;              // edges per tile
constexpr int NT   = E_TOTAL / EB;    // 12500 tiles
constexpr int GRID = 512;             // persistent blocks, 2 per CU
constexpr int TPB  = 512;             // 8 waves: 4 n-groups x 2 e-groups

typedef __attribute__((ext_vector_type(8)))  short bf16x8;
typedef __attribute__((ext_vector_type(16))) float f32x16;

// ---------------- workspace byte offsets ----------------
// bf16 images, n-major rows, bias folded at k=100 (k=8 for W1); act pads carry 1.0.
constexpr size_t WS_CNT = 0;                   // N_NODES f32
constexpr size_t WS_W1  = 200704;              // [128 n][32 B]   (K=16)
constexpr size_t WS_W2  = WS_W1 + 4096;        // [128 n][256 B]  (K=128)
constexpr size_t WS_W3  = WS_W2 + 32768;       // [128 n][256 B]
constexpr size_t WS_W4  = WS_W3 + 32768;       // [256 n][256 B]

// ---------------- LDS byte offsets (64000 B -> 2 blocks/CU) ----------------
constexpr int L_HA  = 0;                 // [64 e][272 B] bf16 (stride 17x16B)
constexpr int L_HB  = 17408;             // [64 e][272 B]
constexpr int L_EA  = 34816;             // [64 e][48 B] bf16 (16 k; 1.0 at k=8)
constexpr int L_XS  = 37888;             // [64 e][80 B] f32 (16 used)
constexpr int L_MSG = 43008;             // 4 slabs x [64 e][80 B] f32 (16 used)
constexpr int L_DST = 63488;             // 2 x 64 i32
constexpr int L_TOT = 64000;

__device__ inline unsigned short bfb(float f) {
    __hip_bfloat16 h = __float2bfloat16(f);
    return __builtin_bit_cast(unsigned short, h);
}
__device__ inline unsigned pk2(float a, float b) {
    return (unsigned)bfb(a) | ((unsigned)bfb(b) << 16);
}
__device__ inline unsigned pk2r(float a, float b) {   // relu + pack
    return pk2(fmaxf(a, 0.f), fmaxf(b, 0.f));
}

// K=128 layer, 32x32x16 MFMA, swapped operands: D[n][e] = sum_k W[n][k] h[e][k].
// A (weights) from registers; B (activations) rows [e][272B].
template<int IN_OFF, int OUT_OFF>
__device__ inline void layer32(char* sm, const bf16x8 (&wf)[8],
                               int wn, int we, int l31, int g)
{
    const int e = 32 * we + l31;
    f32x16 acc = {};
#pragma unroll
    for (int ks = 0; ks < 8; ++ks) {
        const bf16x8 b = *reinterpret_cast<const bf16x8*>(sm + IN_OFF + e * 272 + ks * 32 + g * 16);
        acc = __builtin_amdgcn_mfma_f32_32x32x16_bf16(wf[ks], b, acc, 0, 0, 0);
    }
#pragma unroll
    for (int q = 0; q < 4; ++q) {
        uint2 pk;
        pk.x = pk2r(acc[4 * q + 0], acc[4 * q + 1]);
        pk.y = pk2r(acc[4 * q + 2], acc[4 * q + 3]);
        *reinterpret_cast<uint2*>(sm + OUT_OFF + e * 272 + 64 * wn + 16 * q + 8 * g) = pk;
    }
}

// NOTE: min-waves/EU = 2 (VGPR cap 256). R6 evidence: compiler settles at 128
// VGPR with L2-hitting remat of the weight overflow. (512,4) forced 64 VGPR and
// caused an 880 MB HBM remat storm (R7) — do not tighten this bound.
__global__ __launch_bounds__(TPB, 2)
void edge_kernel(const float* __restrict__ x, const int* __restrict__ eidx,
                 const float* __restrict__ ea, const char* __restrict__ ws,
                 float* __restrict__ out, float* __restrict__ cnt)
{
    extern __shared__ char sm[];
    const int t    = threadIdx.x;
    const int lane = t & 63;
    const int wave = t >> 6;
    const int wn   = wave & 3, we = wave >> 2;   // 4 n-groups x 2 e-groups
    const int l31  = lane & 31, g = lane >> 5;
    int* dsti = reinterpret_cast<int*>(sm + L_DST);

    // ---- weight fragments (A-operands); compiler keeps/remats under its budget ----
    bf16x8 wf1, wf2[8], wf3[8], wf4[2][8];
    {
        const int n = 32 * wn + l31;
        wf1 = *reinterpret_cast<const bf16x8*>(ws + WS_W1 + n * 32 + g * 16);
#pragma unroll
        for (int ks = 0; ks < 8; ++ks) {
            wf2[ks] = *reinterpret_cast<const bf16x8*>(ws + WS_W2 + n * 256 + ks * 32 + g * 16);
            wf3[ks] = *reinterpret_cast<const bf16x8*>(ws + WS_W3 + n * 256 + ks * 32 + g * 16);
        }
#pragma unroll
        for (int mf = 0; mf < 2; ++mf) {
            const int n4 = 64 * wn + 32 * mf + l31;
#pragma unroll
            for (int ks = 0; ks < 8; ++ks)
                wf4[mf][ks] = *reinterpret_cast<const bf16x8*>(ws + WS_W4 + n4 * 256 + ks * 32 + g * 16);
        }
    }

    // ---- constant upper half of EA rows: k=8 -> 1.0, k=9..15 -> 0 ----
    if (t < 64)
        *reinterpret_cast<uint4*>(sm + L_EA + t * 48 + 16) = make_uint4(0x3F80u, 0u, 0u, 0u);

    // ---- stage first tile into registers ----
    float4 eaR, xvR; int dstR = 0;
    {
        const int e0 = blockIdx.x * EB;
        if (t < 128) eaR = *reinterpret_cast<const float4*>(&ea[(size_t)(e0 + (t >> 1)) * 8 + (t & 1) * 4]);
        if (t < 256) {
            const int s = eidx[e0 + (t >> 2)];
            xvR = *reinterpret_cast<const float4*>(&x[(size_t)s * 16 + (t & 3) * 4]);
        }
        if (t < 64) dstR = eidx[E_TOTAL + e0 + t];
    }

    int p = 0;
    bool has_prev = false;
    for (int tile = blockIdx.x; tile < NT; tile += GRID) {
        // ---- S: scatter prev tile's messages; stage this tile; prefetch next ----
        if (has_prev && t < 256) {
            const int e = t >> 2, o0 = (t & 3) * 4;
            const float4 s0 = *reinterpret_cast<const float4*>(sm + L_MSG + 0 * 5120 + e * 80 + o0 * 4);
            const float4 s1 = *reinterpret_cast<const float4*>(sm + L_MSG + 1 * 5120 + e * 80 + o0 * 4);
            const float4 s2 = *reinterpret_cast<const float4*>(sm + L_MSG + 2 * 5120 + e * 80 + o0 * 4);
            const float4 s3 = *reinterpret_cast<const float4*>(sm + L_MSG + 3 * 5120 + e * 80 + o0 * 4);
            const int d = dsti[(p ^ 1) * 64 + e];
            unsafeAtomicAdd(&out[(size_t)d * 16 + o0 + 0], s0.x + s1.x + s2.x + s3.x);
            unsafeAtomicAdd(&out[(size_t)d * 16 + o0 + 1], s0.y + s1.y + s2.y + s3.y);
            unsafeAtomicAdd(&out[(size_t)d * 16 + o0 + 2], s0.z + s1.z + s2.z + s3.z);
            unsafeAtomicAdd(&out[(size_t)d * 16 + o0 + 3], s0.w + s1.w + s2.w + s3.w);
            if ((t & 3) == 0) unsafeAtomicAdd(&cnt[d], 1.0f);
        }
        if (t < 128) {   // ea -> bf16, lower 16B of EA row
            uint2 pk; pk.x = pk2(eaR.x, eaR.y); pk.y = pk2(eaR.z, eaR.w);
            *reinterpret_cast<uint2*>(sm + L_EA + (t >> 1) * 48 + 8 * (t & 1)) = pk;
        }
        if (t < 256)
            *reinterpret_cast<float4*>(sm + L_XS + (t >> 2) * 80 + (t & 3) * 16) = xvR;
        if (t < 64) dsti[p * 64 + t] = dstR;

        const int nxt = tile + GRID;
        if (nxt < NT) {
            const int e0 = nxt * EB;
            if (t < 128) eaR = *reinterpret_cast<const float4*>(&ea[(size_t)(e0 + (t >> 1)) * 8 + (t & 1) * 4]);
            if (t < 256) {
                const int s = eidx[e0 + (t >> 2)];
                xvR = *reinterpret_cast<const float4*>(&x[(size_t)s * 16 + (t & 3) * 4]);
            }
            if (t < 64) dstR = eidx[E_TOTAL + e0 + t];
        }
        __syncthreads();                                            // A

        // ---- L1: K=16 (8 attrs + bias col), EA -> HA ----
        {
            const int e = 32 * we + l31;
            const bf16x8 b = *reinterpret_cast<const bf16x8*>(sm + L_EA + e * 48 + g * 16);
            f32x16 acc = {};
            acc = __builtin_amdgcn_mfma_f32_32x32x16_bf16(wf1, b, acc, 0, 0, 0);
#pragma unroll
            for (int q = 0; q < 4; ++q) {
                uint2 pk;
                pk.x = pk2r(acc[4 * q + 0], acc[4 * q + 1]);
                pk.y = pk2r(acc[4 * q + 2], acc[4 * q + 3]);
                *reinterpret_cast<uint2*>(sm + L_HA + e * 272 + 64 * wn + 16 * q + 8 * g) = pk;
            }
        }
        __syncthreads();                                            // B
        layer32<L_HA, L_HB>(sm, wf2, wn, we, l31, g);               // L2
        __syncthreads();                                            // C
        layer32<L_HB, L_HA>(sm, wf3, wn, we, l31, g);               // L3
        __syncthreads();                                            // D

        // ---- L4: w[e][n] for this wave's 64 n (W4 from regs) + fold x ----
        {
            const int e = 32 * we + l31;
            f32x16 acc4[2] = {};
#pragma unroll
            for (int ks = 0; ks < 8; ++ks) {
                const bf16x8 b = *reinterpret_cast<const bf16x8*>(sm + L_HA + e * 272 + ks * 32 + g * 16);
#pragma unroll
                for (int mf = 0; mf < 2; ++mf)
                    acc4[mf] = __builtin_amdgcn_mfma_f32_32x32x16_bf16(wf4[mf][ks], b, acc4[mf], 0, 0, 0);
            }
            // fold: n = 64wn + 32mf + nloc; i = n>>4 = 4wn + 2mf + (reg>>3); o = n&15
            const float4 xv = *reinterpret_cast<const float4*>(sm + L_XS + e * 80 + wn * 16);
            float pr[8] = {0.f, 0.f, 0.f, 0.f, 0.f, 0.f, 0.f, 0.f};
#pragma unroll
            for (int mf = 0; mf < 2; ++mf)
#pragma unroll
                for (int reg = 0; reg < 16; ++reg) {
                    const float xi = (&xv.x)[2 * mf + (reg >> 3)];
                    const int s = (reg & 3) + 4 * ((reg >> 2) & 1);
                    pr[s] = fmaf(xi, acc4[mf][reg], pr[s]);
                }
            // o = {0..3}+4g at byte 16g ; o = {8..11}+4g at byte 32+16g
            *reinterpret_cast<float4*>(sm + L_MSG + wn * 5120 + e * 80 + 16 * g) =
                make_float4(pr[0], pr[1], pr[2], pr[3]);
            *reinterpret_cast<float4*>(sm + L_MSG + wn * 5120 + e * 80 + 32 + 16 * g) =
                make_float4(pr[4], pr[5], pr[6], pr[7]);
        }
        __syncthreads();                                            // E
        p ^= 1;
        has_prev = true;
    }

    // ---- trailing scatter ----
    if (has_prev && t < 256) {
        const int e = t >> 2, o0 = (t & 3) * 4;
        const float4 s0 = *reinterpret_cast<const float4*>(sm + L_MSG + 0 * 5120 + e * 80 + o0 * 4);
        const float4 s1 = *reinterpret_cast<const float4*>(sm + L_MSG + 1 * 5120 + e * 80 + o0 * 4);
        const float4 s2 = *reinterpret_cast<const float4*>(sm + L_MSG + 2 * 5120 + e * 80 + o0 * 4);
        const float4 s3 = *reinterpret_cast<const float4*>(sm + L_MSG + 3 * 5120 + e * 80 + o0 * 4);
        const int d = dsti[(p ^ 1) * 64 + e];
        unsafeAtomicAdd(&out[(size_t)d * 16 + o0 + 0], s0.x + s1.x + s2.x + s3.x);
        unsafeAtomicAdd(&out[(size_t)d * 16 + o0 + 1], s0.y + s1.y + s2.y + s3.y);
        unsafeAtomicAdd(&out[(size_t)d * 16 + o0 + 2], s0.z + s1.z + s2.z + s3.z);
        unsafeAtomicAdd(&out[(size_t)d * 16 + o0 + 3], s0.w + s1.w + s2.w + s3.w);
        if ((t & 3) == 0) unsafeAtomicAdd(&cnt[d], 1.0f);
    }
}

// bf16 weight images with bias folded (k=100 col; k=8 for W1) + zero cnt
__global__ __launch_bounds__(256)
void prep_kernel(const float* __restrict__ W1, const float* __restrict__ b1,
                 const float* __restrict__ W2, const float* __restrict__ b2,
                 const float* __restrict__ W3, const float* __restrict__ b3,
                 const float* __restrict__ W4, const float* __restrict__ b4,
                 char* __restrict__ ws)
{
    const int id = blockIdx.x * 256 + threadIdx.x;
    if (id < N_NODES) reinterpret_cast<float*>(ws + WS_CNT)[id] = 0.f;
    if (id >= 67584) return;
    if (id < 2048) {                       // W1 img [128 n][16 k]
        const int n = id >> 4, k = id & 15;
        float v = 0.f;
        if (k < 8)        { if (n < 100) v = W1[k * 100 + n]; }
        else if (k == 8)  { v = (n < 100) ? b1[n] : (n == 100 ? 1.f : 0.f); }
        reinterpret_cast<unsigned short*>(ws + WS_W1)[id] = bfb(v);
    } else if (id < 18432) {               // W2 img [128][128]
        const int j = id - 2048, n = j >> 7, k = j & 127;
        float v = 0.f;
        if (k < 100)       { if (n < 100) v = W2[k * 100 + n]; }
        else if (k == 100) { v = (n < 100) ? b2[n] : (n == 100 ? 1.f : 0.f); }
        reinterpret_cast<unsigned short*>(ws + WS_W2)[j] = bfb(v);
    } else if (id < 34816) {               // W3 img [128][128]
        const int j = id - 18432, n = j >> 7, k = j & 127;
        float v = 0.f;
        if (k < 100)       { if (n < 100) v = W3[k * 100 + n]; }
        else if (k == 100) { v = (n < 100) ? b3[n] : (n == 100 ? 1.f : 0.f); }
        reinterpret_cast<unsigned short*>(ws + WS_W3)[j] = bfb(v);
    } else {                               // W4 img [256][128]
        const int j = id - 34816, n = j >> 7, k = j & 127;
        float v = 0.f;
        if (k < 100)       v = W4[k * 256 + n];
        else if (k == 100) v = b4[n];
        reinterpret_cast<unsigned short*>(ws + WS_W4)[j] = bfb(v);
    }
}

// out[n][o] = x[n]@root[:,o] + out[n][o]/max(cnt[n],1) + bias[o]   (in place)
__global__ __launch_bounds__(256)
void node_kernel(const float* __restrict__ x, const float* __restrict__ root,
                 const float* __restrict__ bias, const float* __restrict__ cnt,
                 float* __restrict__ out)
{
    const int n = blockIdx.x * blockDim.x + threadIdx.x;
    if (n >= N_NODES) return;
    float xr[16];
#pragma unroll
    for (int q = 0; q < 4; ++q) {
        const float4 v = *reinterpret_cast<const float4*>(&x[(size_t)n * 16 + 4 * q]);
        xr[4 * q] = v.x; xr[4 * q + 1] = v.y; xr[4 * q + 2] = v.z; xr[4 * q + 3] = v.w;
    }
    const float inv = 1.f / fmaxf(cnt[n], 1.f);
#pragma unroll
    for (int q = 0; q < 4; ++q) {
        float4 o4 = *reinterpret_cast<float4*>(&out[(size_t)n * 16 + 4 * q]);
        float res[4];
#pragma unroll
        for (int j = 0; j < 4; ++j) {
            const int o = 4 * q + j;
            float dot = 0.f;
#pragma unroll
            for (int i = 0; i < 16; ++i)
                dot = fmaf(xr[i], root[i * 16 + o], dot);
            res[j] = dot + (&o4.x)[j] * inv + bias[o];
        }
        *reinterpret_cast<float4*>(&out[(size_t)n * 16 + 4 * q]) = make_float4(res[0], res[1], res[2], res[3]);
    }
}

extern "C" void kernel_launch(void* const* d_in, const int* in_sizes, int n_in,
                              void* d_out, int out_size, void* d_ws, size_t ws_size,
                              hipStream_t stream)
{
    const float* x    = (const float*)d_in[0];
    const int*   eidx = (const int*)  d_in[1];
    const float* ea   = (const float*)d_in[2];
    const float* W1   = (const float*)d_in[3];
    const float* b1   = (const float*)d_in[4];
    const float* W2   = (const float*)d_in[5];
    const float* b2   = (const float*)d_in[6];
    const float* W3   = (const float*)d_in[7];
    const float* b3   = (const float*)d_in[8];
    const float* W4   = (const float*)d_in[9];
    const float* b4   = (const float*)d_in[10];
    const float* root = (const float*)d_in[11];
    const float* bias = (const float*)d_in[12];
    float* out = (float*)d_out;
    char*  ws  = (char*)d_ws;
    float* cnt = (float*)d_ws;

    (void)in_sizes; (void)n_in; (void)ws_size;

    hipFuncSetAttribute((const void*)edge_kernel,
                        hipFuncAttributeMaxDynamicSharedMemorySize, L_TOT);

    hipMemsetAsync(d_out, 0, (size_t)out_size * sizeof(float), stream);

    hipLaunchKernelGGL(prep_kernel, dim3(264), dim3(256), 0, stream,
                       W1, b1, W2, b2, W3, b3, W4, b4, ws);
    hipLaunchKernelGGL(edge_kernel, dim3(GRID), dim3(TPB), L_TOT, stream,
                       x, eidx, ea, ws, out, cnt);
    hipLaunchKernelGGL(node_kernel, dim3((N_NODES + 255) / 256), dim3(256), 0, stream,
                       x, root, bias, cnt, out);
}